// Round 8
// baseline (381.094 us; speedup 1.0000x reference)
//
#include <hip/hip_runtime.h>
#include <stdint.h>

typedef __attribute__((ext_vector_type(8))) short bf16x8;   // 8 bf16 in 4 VGPRs
typedef __attribute__((ext_vector_type(4))) float f32x4;
typedef __attribute__((address_space(1))) void as1_void;
typedef __attribute__((address_space(3))) void as3_void;

#define D_MODEL 1024
#define SEQ     2048
#define BATCH   4
#define HEADS   16
#define HDIM    64

// softmax scale: exp(s/32) = exp2(s * log2e/32); folded into Wq/bq at prep time
#define QSCALE 0.045084220029218407f

__device__ __forceinline__ ushort f2bf(float f) {
  union { float f; unsigned u; } v; v.f = f;
  unsigned u = v.u + 0x7fffu + ((v.u >> 16) & 1u);  // RNE
  return (ushort)(u >> 16);
}

__device__ __forceinline__ void gload_lds16(const void* g, void* l) {
  // width=16: emits global_load_lds_dwordx4; LDS dest = wave-uniform base + lane*16
  __builtin_amdgcn_global_load_lds((as1_void*)(uintptr_t)g, (as3_void*)l, 16, 0, 0);
}

// pack 8 floats -> bf16x8 (truncation) via v_perm
__device__ __forceinline__ bf16x8 pack8(float a0, float a1, float a2, float a3,
                                        float a4, float a5, float a6, float a7) {
  union { uint u[4]; bf16x8 v; } x;
  x.u[0] = __builtin_amdgcn_perm(__float_as_uint(a1), __float_as_uint(a0), 0x07060302);
  x.u[1] = __builtin_amdgcn_perm(__float_as_uint(a3), __float_as_uint(a2), 0x07060302);
  x.u[2] = __builtin_amdgcn_perm(__float_as_uint(a5), __float_as_uint(a4), 0x07060302);
  x.u[3] = __builtin_amdgcn_perm(__float_as_uint(a7), __float_as_uint(a6), 0x07060302);
  return x.v;
}

// ---------- fused prep: X->bf16 | W transpose->bf16 (Wq scaled) | bias concat ----------
__global__ void prep_kernel(const float* __restrict__ X,
                            const float* w0, const float* w1, const float* w2, const float* w3,
                            const float* __restrict__ bq, const float* __restrict__ bk,
                            const float* __restrict__ bv,
                            ushort* __restrict__ Xb, ushort* __restrict__ WT,
                            float* __restrict__ bcat) {
  __shared__ float tile[32][33];
  const int bx = blockIdx.x, t = threadIdx.x;
  if (bx < 8192) {                       // X fp32 -> bf16
    int i = bx * 256 + t;
    float4 f = reinterpret_cast<const float4*>(X)[i];
    ushort4 o;
    o.x = f2bf(f.x); o.y = f2bf(f.y); o.z = f2bf(f.z); o.w = f2bf(f.w);
    reinterpret_cast<ushort4*>(Xb)[i] = o;
  } else if (bx < 12288) {               // weight transpose: 4 weights x 1024 tiles
    int tz = bx - 8192;
    int z = tz >> 10;
    int xy = tz & 1023;
    int bxt = xy & 31, byt = xy >> 5;
    const float* w = (z == 0) ? w0 : (z == 1) ? w1 : (z == 2) ? w2 : w3;
    const float sc = (z == 0) ? QSCALE : 1.0f;
    ushort* o = WT + (size_t)z * D_MODEL * D_MODEL;
    int tx = t & 31, ty = t >> 5;
    int x = bxt * 32 + tx;
    int y0 = byt * 32;
    #pragma unroll
    for (int i = ty; i < 32; i += 8)
      tile[i][tx] = w[(size_t)(y0 + i) * D_MODEL + x];
    __syncthreads();
    #pragma unroll
    for (int i = ty; i < 32; i += 8)
      o[(size_t)(bxt * 32 + i) * D_MODEL + y0 + tx] = f2bf(tile[tx][i] * sc);
  } else {                               // bias concat (12 blocks)
    int i = (bx - 12288) * 256 + t;
    bcat[i] = (i < 1024) ? bq[i] * QSCALE : (i < 2048) ? bk[i - 1024] : bv[i - 2048];
  }
}

// ---------- QKV GEMM (m97 single-buffer): Q -> Qh[b][h][S][64], K -> Kh[b][h][S][64],
// V -> Vt[b][h][d][S] (keys permuted per 64-chunk: col ck*64+c holds key ck*64+g(c),
// g(c)=(c&32)|((c&4)<<2)|((c>>1)&12)|(c&3)) ----------
__global__ __launch_bounds__(256) void gemm_qkv(const ushort* __restrict__ A, const ushort* __restrict__ BT,
                                                const float* __restrict__ bias,
                                                ushort* __restrict__ Qh, ushort* __restrict__ Kh,
                                                ushort* __restrict__ Vt) {
  __shared__ __align__(16) ushort As[128 * 32];
  __shared__ __align__(16) ushort Bs[128 * 32];
  const int K = D_MODEL;
  const int tid  = threadIdx.x;
  const int w    = tid >> 6;
  const int lane = tid & 63;
  const int lo   = lane & 15, quad = lane >> 4;
  const int m0 = blockIdx.y * 128, n0 = blockIdx.x * 128;
  const int ra = lane >> 2;
  const int ca = (lane & 3) * 8;
  const int wm = (w & 1) * 64, wn = (w >> 1) * 64;

  f32x4 acc[4][4];
  #pragma unroll
  for (int i = 0; i < 4; ++i)
    #pragma unroll
    for (int j = 0; j < 4; ++j) acc[i][j] = {0.f, 0.f, 0.f, 0.f};

  for (int k0 = 0; k0 < K; k0 += 32) {
    #pragma unroll
    for (int i = 0; i < 2; ++i) {
      const int j = w * 2 + i;
      gload_lds16(A  + (size_t)(m0 + j * 16 + ra) * K + k0 + ca, &As[j * 512]);
      gload_lds16(BT + (size_t)(n0 + j * 16 + ra) * K + k0 + ca, &Bs[j * 512]);
    }
    __syncthreads();
    bf16x8 af[4], bfv[4];
    #pragma unroll
    for (int mi = 0; mi < 4; ++mi) af[mi]  = *(const bf16x8*)&As[(wm + mi * 16 + lo) * 32 + quad * 8];
    #pragma unroll
    for (int ni = 0; ni < 4; ++ni) bfv[ni] = *(const bf16x8*)&Bs[(wn + ni * 16 + lo) * 32 + quad * 8];
    #pragma unroll
    for (int mi = 0; mi < 4; ++mi)
      #pragma unroll
      for (int ni = 0; ni < 4; ++ni)
        acc[mi][ni] = __builtin_amdgcn_mfma_f32_16x16x32_bf16(af[mi], bfv[ni], acc[mi][ni], 0, 0, 0);
    __syncthreads();
  }

  if (blockIdx.x < 16) {
    // Q,K part: head-blocked [b][h][S][64] stores
    #pragma unroll
    for (int ni = 0; ni < 4; ++ni) {
      const int col = n0 + wn + ni * 16 + lo;
      const float bv = bias[col];
      const int head = (col >> 6) & 15;
      const int d = col & 63;
      ushort* dst = (col < 1024) ? Qh : Kh;
      #pragma unroll
      for (int mi = 0; mi < 4; ++mi) {
        #pragma unroll
        for (int r = 0; r < 4; ++r) {
          const int row = m0 + wm + mi * 16 + quad * 4 + r;
          const int bidx = row >> 11, srow = row & 2047;
          dst[(size_t)((bidx * HEADS + head) * SEQ + srow) * HDIM + d] = f2bf(acc[mi][ni][r] + bv);
        }
      }
    }
  } else {
    // V part: permuted-transpose store into Vt[b][h][d][SEQ]
    #pragma unroll
    for (int ni = 0; ni < 4; ++ni) {
      const int col  = n0 + wn + ni * 16 + lo;
      const int vcol = col - 2048;
      const int hh = vcol >> 6, d = vcol & 63;
      const float bv = bias[col];
      #pragma unroll
      for (int mi = 0; mi < 4; ++mi) {
        const int base = m0 + wm + mi * 16;
        const int brow = base + quad * 4;
        const int bidx = brow >> 11;
        const int srow = brow & 2047;
        const int ck   = srow >> 6;
        const int c0   = (base & 32) + (quad << 3) + ((base >> 2) & 4);
        ushort e0 = f2bf(acc[mi][ni][0] + bv);
        ushort e1 = f2bf(acc[mi][ni][1] + bv);
        ushort e2 = f2bf(acc[mi][ni][2] + bv);
        ushort e3 = f2bf(acc[mi][ni][3] + bv);
        uint2 pk;
        pk.x = (uint)e0 | ((uint)e1 << 16);
        pk.y = (uint)e2 | ((uint)e3 << 16);
        *(uint2*)&Vt[(size_t)((bidx * HEADS + hh) * HDIM + d) * SEQ + ck * 64 + c0] = pk;
      }
    }
  }
}

// ---------- final projection GEMM (m97 single-buffer): fp32 out + bias ----------
__global__ __launch_bounds__(256) void gemm_bt_f32(const ushort* __restrict__ A, const ushort* __restrict__ BT,
                                                   const float* __restrict__ bias, float* __restrict__ C) {
  __shared__ __align__(16) ushort As[128 * 32];
  __shared__ __align__(16) ushort Bs[128 * 32];
  const int K = D_MODEL, N = D_MODEL;
  const int tid  = threadIdx.x;
  const int w    = tid >> 6;
  const int lane = tid & 63;
  const int lo   = lane & 15, quad = lane >> 4;
  const int m0 = blockIdx.y * 128, n0 = blockIdx.x * 128;
  const int ra = lane >> 2;
  const int ca = (lane & 3) * 8;
  const int wm = (w & 1) * 64, wn = (w >> 1) * 64;

  f32x4 acc[4][4];
  #pragma unroll
  for (int i = 0; i < 4; ++i)
    #pragma unroll
    for (int j = 0; j < 4; ++j) acc[i][j] = {0.f, 0.f, 0.f, 0.f};

  for (int k0 = 0; k0 < K; k0 += 32) {
    #pragma unroll
    for (int i = 0; i < 2; ++i) {
      const int j = w * 2 + i;
      gload_lds16(A  + (size_t)(m0 + j * 16 + ra) * K + k0 + ca, &As[j * 512]);
      gload_lds16(BT + (size_t)(n0 + j * 16 + ra) * K + k0 + ca, &Bs[j * 512]);
    }
    __syncthreads();
    bf16x8 af[4], bfv[4];
    #pragma unroll
    for (int mi = 0; mi < 4; ++mi) af[mi]  = *(const bf16x8*)&As[(wm + mi * 16 + lo) * 32 + quad * 8];
    #pragma unroll
    for (int ni = 0; ni < 4; ++ni) bfv[ni] = *(const bf16x8*)&Bs[(wn + ni * 16 + lo) * 32 + quad * 8];
    #pragma unroll
    for (int mi = 0; mi < 4; ++mi)
      #pragma unroll
      for (int ni = 0; ni < 4; ++ni)
        acc[mi][ni] = __builtin_amdgcn_mfma_f32_16x16x32_bf16(af[mi], bfv[ni], acc[mi][ni], 0, 0, 0);
    __syncthreads();
  }

  #pragma unroll
  for (int ni = 0; ni < 4; ++ni) {
    const int col = n0 + wn + ni * 16 + lo;
    const float bv = bias[col];
    #pragma unroll
    for (int mi = 0; mi < 4; ++mi) {
      #pragma unroll
      for (int r = 0; r < 4; ++r) {
        const int row = m0 + wm + mi * 16 + quad * 4 + r;
        C[(size_t)row * N + col] = acc[mi][ni][r] + bv;
      }
    }
  }
}

// ---------- flash attention, split-K + wave-private staging (no hot-loop barriers) ----------
// block = 256 threads = 4 waves; waves (0,1) share q-tile 0 (64 q), waves (2,3) q-tile 1.
// Even wave handles keys [0,1024), odd wave keys [1024,2048). Each wave stages 32-key chunks
// into its private 8KB LDS region (Ks 4KB + Vs 4KB); ordering is wave-level s_waitcnt only.
// S^T via mfma(A=K,B=Q); exp'd scores feed PV A-operand from registers (Vt key permutation).
// Un-normalized partials combine by addition at the end (8 barriers), even wave stores.
__global__ __launch_bounds__(256, 4) void attn_kernel(const ushort* __restrict__ Qh,
                                                      const ushort* __restrict__ Kh,
                                                      const ushort* __restrict__ Vt,
                                                      ushort* __restrict__ Og) {
  __shared__ __align__(16) ushort LDSbuf[4 * 4096];   // 4 waves x 8KB

  const int tid  = threadIdx.x;
  const int w    = tid >> 6, lane = tid & 63;
  const int lo   = lane & 15, quad = lane >> 4;
  const int bh = blockIdx.x;                   // b*16+h; linear-id%8 = bh%8 -> XCD locality
  const int b = bh >> 4, h = bh & 15;
  const int qbase = blockIdx.y * 128 + (w >> 1) * 64;
  const int kb = (w & 1) * 1024;               // this wave's key half

  ushort* Ks = &LDSbuf[w * 4096];              // [32 key][64 d], seg-swizzled (8 segs, key&7)
  ushort* Vs = &LDSbuf[w * 4096 + 2048];       // [64 d][32 keyslot], seg-swizzled (4 segs, d&3)

  const ushort* Qbh = Qh + (size_t)bh * SEQ * HDIM;
  const ushort* Kbh = Kh + (size_t)bh * SEQ * HDIM;
  const ushort* Vbh = Vt + (size_t)bh * HDIM * SEQ;

  // Q fragments (B-operand layout: n=lo=q, k=quad*8+j); pre-scaled by QSCALE via Wq
  bf16x8 qf[4][2];
  #pragma unroll
  for (int qg = 0; qg < 4; ++qg) {
    const ushort* qp = Qbh + (size_t)(qbase + qg * 16 + lo) * HDIM + quad * 8;
    qf[qg][0] = *(const bf16x8*)(qp);
    qf[qg][1] = *(const bf16x8*)(qp + 32);
  }

  f32x4 acc[4][4];
  #pragma unroll
  for (int qg = 0; qg < 4; ++qg)
    #pragma unroll
    for (int t = 0; t < 4; ++t) acc[qg][t] = {0.f, 0.f, 0.f, 0.f};
  float lsum[4] = {0.f, 0.f, 0.f, 0.f};

  // staging lane roles (chunk-invariant)
  const int kr_ = lane >> 3, kseg = lane & 7;   // Ks: 8 key-rows/slot, 128B rows
  const int vr_ = lane >> 2, vseg = lane & 3;   // Vs: 16 d-rows/slot, 64B rows

  for (int ck = 0; ck < 32; ++ck) {
    const int key0 = kb + ck * 32;
    // stage this wave's 32-key chunk (8KB, 8 DMA instructions)
    #pragma unroll
    for (int j = 0; j < 4; ++j) {
      const int r = j * 8 + kr_;
      gload_lds16(Kbh + (size_t)(key0 + r) * HDIM + (kseg ^ (r & 7)) * 8, &Ks[j * 512]);
    }
    #pragma unroll
    for (int j = 0; j < 4; ++j) {
      const int d = j * 16 + vr_;
      gload_lds16(Vbh + (size_t)d * SEQ + key0 + (vseg ^ (d & 3)) * 8, &Vs[j * 512]);
    }
    __asm__ volatile("s_waitcnt vmcnt(0)" ::: "memory");   // wave-level: DMA landed

    // K fragments (A-operand: m=key=sub*16+lo, k=d=hh*32+quad*8+j)
    bf16x8 kf[2][2];
    #pragma unroll
    for (int sub = 0; sub < 2; ++sub) {
      const ushort* krow = &Ks[(sub * 16 + lo) * 64];
      kf[sub][0] = *(const bf16x8*)(krow + ((quad ^ (lo & 7)) * 8));
      kf[sub][1] = *(const bf16x8*)(krow + (((4 + quad) ^ (lo & 7)) * 8));
    }

    // phase A: S^T per q-group, exp + pack in registers
    bf16x8 af[4];
    #pragma unroll
    for (int qg = 0; qg < 4; ++qg) {
      f32x4 s[2];
      s[0] = {0.f, 0.f, 0.f, 0.f};
      s[1] = {0.f, 0.f, 0.f, 0.f};
      #pragma unroll
      for (int sub = 0; sub < 2; ++sub) {
        s[sub] = __builtin_amdgcn_mfma_f32_16x16x32_bf16(kf[sub][0], qf[qg][0], s[sub], 0, 0, 0);
        s[sub] = __builtin_amdgcn_mfma_f32_16x16x32_bf16(kf[sub][1], qf[qg][1], s[sub], 0, 0, 0);
      }
      float p[2][4];
      #pragma unroll
      for (int sub = 0; sub < 2; ++sub)
        #pragma unroll
        for (int r = 0; r < 4; ++r) p[sub][r] = __builtin_amdgcn_exp2f(s[sub][r]);
      lsum[qg] += (p[0][0] + p[0][1]) + (p[0][2] + p[0][3]) +
                  (p[1][0] + p[1][1]) + (p[1][2] + p[1][3]);
      af[qg] = pack8(p[0][0], p[0][1], p[0][2], p[0][3], p[1][0], p[1][1], p[1][2], p[1][3]);
    }

    // phase B: PV (A = exp'd scores, B = V^T from LDS; K=32 -> one MFMA per (qg,t))
    #pragma unroll
    for (int t = 0; t < 4; ++t) {
      const int d = t * 16 + lo;
      bf16x8 vf = *(const bf16x8*)&Vs[d * 32 + ((quad ^ (d & 3)) * 8)];
      #pragma unroll
      for (int qg = 0; qg < 4; ++qg)
        acc[qg][t] = __builtin_amdgcn_mfma_f32_16x16x32_bf16(af[qg], vf, acc[qg][t], 0, 0, 0);
    }
  }

  // ---- split-K combine: odd wave writes partials into its own LDS region, even wave adds ----
  float* lred = (float*)&LDSbuf[(w | 1) * 4096];   // odd partner's 8KB region as 2048 f32
  #pragma unroll
  for (int qg = 0; qg < 4; ++qg) {
    __syncthreads();
    if (w & 1) {
      f32x4* dst = (f32x4*)(lred + lane * 16);
      dst[0] = acc[qg][0]; dst[1] = acc[qg][1];
      dst[2] = acc[qg][2]; dst[3] = acc[qg][3];
      lred[1024 + lane] = lsum[qg];
    }
    __syncthreads();
    if (!(w & 1)) {
      const f32x4* src = (const f32x4*)(lred + lane * 16);
      acc[qg][0] += src[0]; acc[qg][1] += src[1];
      acc[qg][2] += src[2]; acc[qg][3] += src[3];
      lsum[qg] += lred[1024 + lane];
    }
  }

  if (w & 1) return;   // writers done

  // epilogue: lsum lives at lane lo = q; reduce across quads, redistribute, store
  #pragma unroll
  for (int qg = 0; qg < 4; ++qg) {
    float v = lsum[qg];
    v += __shfl_xor(v, 16);
    v += __shfl_xor(v, 32);
    float linv[4];
    #pragma unroll
    for (int r = 0; r < 4; ++r) linv[r] = 1.0f / __shfl(v, quad * 4 + r);
    #pragma unroll
    for (int t = 0; t < 4; ++t)
      #pragma unroll
      for (int r = 0; r < 4; ++r)
        Og[(size_t)(b * SEQ + qbase + qg * 16 + quad * 4 + r) * D_MODEL + h * HDIM + t * 16 + lo] =
            f2bf(acc[qg][t][r] * linv[r]);
  }
}

extern "C" void kernel_launch(void* const* d_in, const int* in_sizes, int n_in,
                              void* d_out, int out_size, void* d_ws, size_t ws_size,
                              hipStream_t stream) {
  const float* X  = (const float*)d_in[0];
  const float* Wq = (const float*)d_in[1];
  const float* bq = (const float*)d_in[2];
  const float* Wk = (const float*)d_in[3];
  const float* bk = (const float*)d_in[4];
  const float* Wv = (const float*)d_in[5];
  const float* bv = (const float*)d_in[6];
  const float* Wo = (const float*)d_in[7];
  const float* bo = (const float*)d_in[8];
  float* out = (float*)d_out;
  char* ws = (char*)d_ws;

  // workspace (88 MB):
  //   [0,16M)   Xb  (bf16 X)
  //   [16,24M)  WT  (4x bf16 transposed weights q|k|v|o; Wq pre-scaled)
  //   [24,40M)  Qh  bf16 [b][h][S][64]
  //   [40,56M)  Kh  bf16 [b][h][S][64]
  //   [56,72M)  Vt  bf16 [b][h][64][S] (permuted keys)
  //   [72,88M)  Ob  bf16 [8192][1024]; head transiently holds bcat (dead before attn writes Ob)
  ushort* Xb  = (ushort*)(ws);
  ushort* WT  = (ushort*)(ws + 16777216);
  ushort* Qhb = (ushort*)(ws + 25165824);
  ushort* Khb = (ushort*)(ws + 41943040);
  ushort* Vtb = (ushort*)(ws + 58720256);
  ushort* Ob  = (ushort*)(ws + 75497472);
  float*  bcat = (float*)(ws + 75497472);
  const int WSTRIDE = D_MODEL * D_MODEL;

  // 1) fused prep: X->bf16, weight transposes, bias concat
  prep_kernel<<<12300, 256, 0, stream>>>(X, Wq, Wk, Wv, Wo, bq, bk, bv, Xb, WT, bcat);

  // 2) fused QKV projection; Q/K head-blocked, V written straight to Vt (permuted transpose)
  gemm_qkv<<<dim3(24, 64), 256, 0, stream>>>(Xb, WT, bcat, Qhb, Khb, Vtb);

  // 3) flash attention (split-K, wave-private staging, XCD-swizzled grid)
  attn_kernel<<<dim3(BATCH * HEADS, SEQ / 128), 256, 0, stream>>>(Qhb, Khb, Vtb, Ob);

  // 4) output projection (fp32 out + bias)
  gemm_bt_f32<<<dim3(8, 64), 256, 0, stream>>>(Ob, WT + 3 * WSTRIDE, bo, out);
}